// Round 5
// baseline (98.265 us; speedup 1.0000x reference)
//
#include <hip/hip_runtime.h>

#define NFILT 80
#define NBINS 257            // 512/2+1
#define NPTS  82             // binpoints
#define ROWS  64             // rows per tile (= lanes per wave)
#define BLOCK 512            // 8 waves
#define NW    8
#define GRID  256            // 1 block per CU
#define OPAD  81             // sout row stride (17*r+f mod 32 -> conflict-free)
#define CHUNKS 4112          // 64*257/4 float4 chunks per tile
#define CHUNKS_PAD 4160      // buffer padded for wave0's 9th DMA instr spill
// d_ws layout (4B units): [0..80] l[] ints; [81..89] c[] ints; [96..609] W floats
#define WS_L 0
#define WS_C 81
#define WS_W 96

// ---------------- prep: sort binpoints, build per-bin weight tables ---------
// W[2k]=wr[k] (rise weight of the filter whose rise-region holds k),
// W[2k+1]=wf[k] (fall weight of the filter whose fall-region holds k).
// l[s]=floor(b[s]); c[w]= segment cut index for wave w (segment-aligned).
__global__ void prep_kernel(const float* __restrict__ bp,
                            int* __restrict__ wsi, float* __restrict__ wsf) {
    __shared__ float b[NPTS];
    __shared__ int   l[NPTS];
    int tid = threadIdx.x;
    if (tid == 0) {
        float tmp[NPTS];
        for (int i = 0; i < NPTS; ++i) tmp[i] = bp[i];
        for (int i = 1; i < NPTS; ++i) {            // insertion sort, 82 elems
            float v = tmp[i]; int j = i - 1;
            while (j >= 0 && tmp[j] > v) { tmp[j+1] = tmp[j]; --j; }
            tmp[j+1] = v;
        }
        for (int i = 0; i < NPTS; ++i) b[i] = tmp[i];
    }
    __syncthreads();
    if (tid < NPTS) l[tid] = (int)floorf(b[tid]);
    __syncthreads();
    if (tid < 81) wsi[WS_L + tid] = l[tid];
    if (tid == 0) {
        int c[NW + 1];
        c[0] = 0; c[NW] = 80;
        int span = l[80] - l[0];
        for (int w = 1; w < NW; ++w) {
            int target = l[0] + (int)((long long)span * w / NW);
            int s = c[w-1] + 2;                     // strictly increasing by >=2
            int hi = 80 - 2 * (NW - w);
            while (s < hi && l[s] < target) ++s;
            c[w] = s;
        }
        for (int w = 0; w <= NW; ++w) wsi[WS_C + w] = c[w];
    }
    if (tid < NBINS) {
        int k = tid;
        float wr = 0.f, wf = 0.f;
        if (k >= l[0] && k < l[80]) {
            int s = 0;
            while (!(k >= l[s] && k < l[s+1])) ++s; // segment containing k
            float d = b[s+1] - b[s];
            float D = d * d;
            float invD = (D == 0.f) ? 1.f : 1.f / D;
            if (s <= 78) wr = ((float)k - b[s]) * invD;     // rise of filter s
            if (s >= 1)  wf = (b[s+1] - (float)k) * invD;   // fall of filter s-1
        }
        wsf[WS_W + 2*k]   = wr;
        wsf[WS_W + 2*k+1] = wf;
    }
}

// ------------------------------- main kernel --------------------------------
__device__ __forceinline__ void stage(const float* __restrict__ x, int tg,
                                      float* ldst, int tid, int wv, int lane) {
    const float* gsrc = x + (size_t)tg * (ROWS * NBINS);
#pragma unroll
    for (int j = 0; j < 8; ++j) {                 // chunks 0..4095
        int ci = tid + j * BLOCK;
        __builtin_amdgcn_global_load_lds(
            (const __attribute__((address_space(1))) void*)(gsrc + ci * 4),
            (__attribute__((address_space(3))) void*)(ldst + ci * 4), 16, 0, 0);
    }
    if (wv == 0) {                                // chunks 4096..4111 (+pad)
        int ci = 4096 + lane;
        int cs = ci <= 4111 ? ci : 4111;          // clamp src; pad lands in slack
        __builtin_amdgcn_global_load_lds(
            (const __attribute__((address_space(1))) void*)(gsrc + cs * 4),
            (__attribute__((address_space(3))) void*)(ldst + ci * 4), 16, 0, 0);
    }
}

__global__ __launch_bounds__(BLOCK, 2) void filter_kernel(
        const float* __restrict__ x, const int* __restrict__ wsi,
        const float* __restrict__ wsf, float* __restrict__ out, int tpb) {
    __shared__ __align__(16) float sx[2][CHUNKS_PAD * 4];  // 2 x 66560 B
    __shared__ float sout[ROWS * OPAD];                    // 20736 B
    __shared__ __align__(8) float sw[2 * NBINS];           // 2056 B
    __shared__ int   sli[81];
    __shared__ int   slc[NW + 1];
    __shared__ float sh[(NW - 1) * ROWS];                  // handoffs
    // total ~158.0 KB -> 1 block/CU, 8 waves

    const int tid  = threadIdx.x;
    const int lane = tid & 63;
    const int wv   = tid >> 6;
    const int tg0  = blockIdx.x * tpb;

    // ---- prologue: tables -> LDS, DMA T0 ----
    if (tid < 81) sli[tid] = wsi[WS_L + tid];
    if (tid < NW + 1) slc[tid] = wsi[WS_C + tid];
    for (int i = tid; i < 2 * NBINS; i += BLOCK) sw[i] = wsf[WS_W + i];
    stage(x, tg0, &sx[0][0], tid, wv, lane);
    __syncthreads();                       // drains tables + T0 (once, prologue only)

    const int s0  = __builtin_amdgcn_readfirstlane(slc[wv]);       // start segment
    const int cB  = __builtin_amdgcn_readfirstlane(slc[wv + 1]);   // end segment
    const int qlo = __builtin_amdgcn_readfirstlane(sli[s0]);       // k range
    const int qhi = __builtin_amdgcn_readfirstlane(sli[cB]);

    if (tpb > 1) stage(x, tg0 + 1, &sx[1][0], tid, wv, lane);      // T1 in flight

    const float2* swp = (const float2*)sw;

    for (int tl = 0; tl < tpb; ++tl) {
        const int cur = tl & 1;
        // invariant at loop head: T_tl fully landed (drained at tl-1's post-store
        // wait + barrier); T_{tl+1} in flight.

        // ---- compute: one streaming sweep over this wave's k-range ----
        const float* xr = &sx[cur][lane * NBINS];
        int s = s0;
        int k = qlo;
        int next = __builtin_amdgcn_readfirstlane(sli[s0 + 1]);
        float r_prev = 0.f, racc = 0.f, facc = 0.f;
        if (k < qhi) {
            float xv  = xr[k];
            float2 w2 = swp[k];
            while (k < qhi) {
                float  xn = xr[k + 1];             // 1-deep prefetch (k+1<=256 safe)
                float2 wn = swp[k + 1];
                while (k == next) {                // wave-uniform boundary crossing
                    if (s >= 1) sout[lane * OPAD + (s - 1)] = r_prev + facc;
                    r_prev = racc; racc = 0.f; facc = 0.f;
                    ++s;
                    next = __builtin_amdgcn_readfirstlane(sli[s + 1]);
                }
                racc = fmaf(xv, w2.x, racc);
                facc = fmaf(xv, w2.y, facc);
                xv = xn; w2 = wn;
                ++k;
            }
        }
        while (s <= cB - 1) {                      // drain pending (+empty segs)
            if (s >= 1) sout[lane * OPAD + (s - 1)] = r_prev + facc;
            r_prev = racc; racc = 0.f; facc = 0.f;
            ++s;
        }
        if (wv < NW - 1) sh[wv * ROWS + lane] = r_prev;   // rise-sum handoff
        if (wv == 0) {
            sout[lane * OPAD + 0]  = xr[0];        // filtered[:,:,0] = x[:,:,0]
            sout[lane * OPAD + 79] = 0.f;          // fbank row 79 is zeros
        }
        asm volatile("s_waitcnt lgkmcnt(0)" ::: "memory");
        __builtin_amdgcn_s_barrier();              // B2: emissions visible
        __builtin_amdgcn_sched_barrier(0);

        // ---- issue DMA for tile tl+2 into the buffer we just finished ----
        if (tl + 2 < tpb) stage(x, tg0 + tl + 2, &sx[cur][0], tid, wv, lane);

        // ---- fixup: add handoffs to the cut-straddling filters ----
        if (tid < (NW - 1) * ROWS) {
            int wcut = tid >> 6;                   // 0..6
            int r    = tid & 63;
            int c    = slc[wcut + 1];
            sout[r * OPAD + (c - 1)] += sh[wcut * ROWS + r];
        }
        asm volatile("s_waitcnt lgkmcnt(0)" ::: "memory");
        __builtin_amdgcn_s_barrier();              // B3: fixup visible
        __builtin_amdgcn_sched_barrier(0);

        // ---- coalesced store of the 64x80 tile ----
        float* ob = out + (size_t)(tg0 + tl) * (ROWS * NFILT);
#pragma unroll
        for (int j = 0; j < (ROWS * NFILT) / BLOCK; ++j) {   // 10 per thread
            int i = tid + j * BLOCK;
            int r = i / NFILT;
            ob[i] = sout[r * OPAD + (i - r * NFILT)];
        }

        // ---- single counted wait: drain T_{tl+1} + my stores, keep T_{tl+2} ----
        if (tl + 2 < tpb) {
            if (wv == 0) asm volatile("s_waitcnt vmcnt(9)" ::: "memory");
            else         asm volatile("s_waitcnt vmcnt(8)" ::: "memory");
        } else {
            asm volatile("s_waitcnt vmcnt(0)" ::: "memory");
        }
        __builtin_amdgcn_sched_barrier(0);
        asm volatile("s_waitcnt lgkmcnt(0)" ::: "memory");
        __builtin_amdgcn_s_barrier();              // B4: sout free, next tile ready
        __builtin_amdgcn_sched_barrier(0);
    }
}

extern "C" void kernel_launch(void* const* d_in, const int* in_sizes, int n_in,
                              void* d_out, int out_size, void* d_ws, size_t ws_size,
                              hipStream_t stream) {
    const float* x  = (const float*)d_in[0];
    const float* bp = (const float*)d_in[1];
    float* out = (float*)d_out;
    int*   wsi = (int*)d_ws;
    float* wsf = (float*)d_ws;   // disjoint index regions

    const int nrows = in_sizes[0] / NBINS;   // 131072
    const int tiles = nrows / ROWS;          // 2048
    const int tpb   = tiles / GRID;          // 8

    prep_kernel<<<1, 320, 0, stream>>>(bp, wsi, wsf);
    filter_kernel<<<GRID, BLOCK, 0, stream>>>(x, wsi, wsf, out, tpb);
}

// Round 6
// 67.403 us; speedup vs baseline: 1.4579x; 1.4579x over previous
//
#include <hip/hip_runtime.h>

#define NFILT 80
#define NBINS 257            // 512/2+1
#define NPTS  82             // binpoints
#define ROWS  64             // rows per tile (= lanes)
#define BLOCK 512            // 8 waves
#define NW    8
#define GRID  256            // 1 block per CU
#define CHUNKS 4112          // 64*257/4 float4 chunks per tile
#define CHUNKS_PAD 4160      // pad for wave0's clamped 9th DMA instr
#define TFLOAT (ROWS * NBINS)

// Async DMA one tile (66KB) global->LDS. 8 instrs/thread + 1 for wave0.
// LDS dest is linear in lane order (wave-uniform base + lane*16) as required.
__device__ __forceinline__ void stage(const float* __restrict__ x, int tg,
                                      float* ldst, int tid, int wv, int lane) {
    const float* gsrc = x + (size_t)tg * TFLOAT;
#pragma unroll
    for (int j = 0; j < 8; ++j) {                  // chunks 0..4095
        int ci = tid + j * BLOCK;
        __builtin_amdgcn_global_load_lds(
            (const __attribute__((address_space(1))) void*)(gsrc + ci * 4),
            (__attribute__((address_space(3))) void*)(ldst + ci * 4), 16, 0, 0);
    }
    if (wv == 0) {                                 // chunks 4096..4111 (+pad)
        int ci = 4096 + lane;
        int cs = ci <= 4111 ? ci : 4111;           // clamp src; excess -> pad
        __builtin_amdgcn_global_load_lds(
            (const __attribute__((address_space(1))) void*)(gsrc + cs * 4),
            (__attribute__((address_space(3))) void*)(ldst + ci * 4), 16, 0, 0);
    }
}

// Per-bin weight streaming: bin k in segment s ([l[s],l[s+1])) contributes
// wr[k] to filter s (rise) and wf[k] to filter s-1 (fall). Each wave owns a
// contiguous filter range [fa,fb) and sweeps segments fa..fb (one-segment
// overlap with neighbors -> no cross-wave handoff). All loop bounds are
// wave-uniform (scalar control). Results stored straight to global.
__global__ __launch_bounds__(BLOCK, 2) void filter_kernel(
        const float* __restrict__ x, const float* __restrict__ bp,
        float* __restrict__ out, int tiles) {
    __shared__ __align__(16) float sx[2][CHUNKS_PAD * 4];  // 2 x 66560 B
    __shared__ __align__(8)  float sw[2 * NBINS];          // 2056 B
    __shared__ float sb[NPTS];
    __shared__ int   sli[NPTS];                            // floor(b[s]), 0..80
    __shared__ int   sflag;
    // total ~136 KB -> 1 block/CU, 8 waves

    const int tid  = threadIdx.x;
    const int lane = tid & 63;
    const int wv   = __builtin_amdgcn_readfirstlane(tid >> 6);

    const int bid  = blockIdx.x;
    const int base = tiles / GRID, rem = tiles % GRID;
    const int t0   = bid * base + min(bid, rem);
    const int cnt  = base + (bid < rem ? 1 : 0);
    if (cnt <= 0) return;

    // ---- prologue: T0 DMA first, prep tables under its latency ----
    stage(x, t0, &sx[0][0], tid, wv, lane);
    if (tid == 0) sflag = 0;
    if (tid < NPTS) sb[tid] = bp[tid];
    for (int i = tid; i < 2 * NBINS; i += BLOCK) sw[i] = 0.f;
    __syncthreads();                       // (drains T0 + bp; prologue only)
    if (tid < NPTS - 1 && sb[tid] > sb[tid + 1]) sflag = 1;
    __syncthreads();
    if (sflag) {                           // input unsorted (not expected)
        if (tid == 0) {
            for (int i = 1; i < NPTS; ++i) {
                float v = sb[i]; int j = i - 1;
                while (j >= 0 && sb[j] > v) { sb[j + 1] = sb[j]; --j; }
                sb[j + 1] = v;
            }
        }
        __syncthreads();
    }
    if (tid <= 80) sli[tid] = (int)floorf(sb[tid]);
    __syncthreads();
    if (tid < 80) {                        // thread s fills its segment's bins
        int s  = tid;
        int k0 = sli[s], k1 = sli[s + 1];
        float bs = sb[s], bs1 = sb[s + 1];
        float d = bs1 - bs, D = d * d;
        float invD = (D == 0.f) ? 1.f : 1.f / D;
        for (int k = k0; k < k1; ++k) {
            sw[2 * k]     = (s <= 78) ? ((float)k - bs) * invD : 0.f;  // rise(s)
            sw[2 * k + 1] = (s >= 1)  ? (bs1 - (float)k) * invD : 0.f; // fall(s-1)
        }
    }
    __syncthreads();                       // tables visible; T0 landed

    if (cnt > 1) stage(x, t0 + 1, &sx[1][0], tid, wv, lane);  // T1 in flight

    const float2* swp = (const float2*)sw;
    const int fa = (79 * wv) / NW;         // filter range [fa, fb)
    const int fb = (79 * (wv + 1)) / NW;   // c = {0,9,19,29,39,49,59,69,79}

    for (int tl = 0; tl < cnt; ++tl) {
        // invariant: T_tl landed (all waves), T_{tl+1} in flight (8|9/thread)
        const float* xr = &sx[tl & 1][lane * NBINS];
        float* orow = out + (size_t)(t0 + tl) * (ROWS * NFILT) + lane * NFILT;

        // ---- compute: sweep segments fa..fb, emit filters fa..fb-1 ----
        int k = __builtin_amdgcn_readfirstlane(sli[fa]);
        float r_prev = 0.f;
        for (int s = fa; s <= fb; ++s) {
            const int k1 = __builtin_amdgcn_readfirstlane(sli[s + 1]);
            float racc = 0.f, facc = 0.f;
            while (k < k1) {
                float  xv = xr[k];
                float2 w2 = swp[k];        // broadcast (same addr all lanes)
                racc = fmaf(xv, w2.x, racc);
                facc = fmaf(xv, w2.y, facc);
                ++k;
            }
            if (s > fa) {
                int f = s - 1;             // rise(seg f) + fall(seg f+1)
                if (f > 0) orow[f] = r_prev + facc;   // f==0 overwritten below
            }
            r_prev = racc;
        }
        if (wv == 0) {
            orow[0] = xr[0];               // filtered[:,:,0] = x[:,:,0]
            orow[NFILT - 1] = 0.f;         // fbank row 79 is zeros
        }

        if (tl == cnt - 1) break;

        asm volatile("s_waitcnt lgkmcnt(0)" ::: "memory");
        __builtin_amdgcn_s_barrier();      // B1: all waves done reading sx[cur]
        __builtin_amdgcn_sched_barrier(0);

        if (tl + 2 < cnt) {
            stage(x, t0 + tl + 2, &sx[tl & 1][0], tid, wv, lane);
            // newest 8|9 ops are T_{tl+2}: keep in flight, drain T_{tl+1}+stores
            if (wv == 0) asm volatile("s_waitcnt vmcnt(9)" ::: "memory");
            else         asm volatile("s_waitcnt vmcnt(8)" ::: "memory");
        } else {
            asm volatile("s_waitcnt vmcnt(0)" ::: "memory");
        }
        __builtin_amdgcn_sched_barrier(0);
        __builtin_amdgcn_s_barrier();      // B2: T_{tl+1} landed for all waves
        __builtin_amdgcn_sched_barrier(0);
    }
}

extern "C" void kernel_launch(void* const* d_in, const int* in_sizes, int n_in,
                              void* d_out, int out_size, void* d_ws, size_t ws_size,
                              hipStream_t stream) {
    const float* x  = (const float*)d_in[0];
    const float* bp = (const float*)d_in[1];
    float* out = (float*)d_out;

    const int nrows = in_sizes[0] / NBINS;   // 131072
    const int tiles = nrows / ROWS;          // 2048

    filter_kernel<<<GRID, BLOCK, 0, stream>>>(x, bp, out, tiles);
}

// Round 7
// 50.622 us; speedup vs baseline: 1.9412x; 1.3315x over previous
//
#include <hip/hip_runtime.h>

#define NFILT 80
#define NBINS 257            // 512/2+1
#define NPTS  82             // binpoints
#define ROWS  64             // rows per tile (= lanes)
#define BLOCK 512            // 8 waves
#define NW    8
#define GRID  256            // 1 block per CU
#define OPAD  81             // sout row stride: bank=(17*lane+f)%32, conflict-free
#define CHUNKS 4112          // 64*257/4 float4 chunks per tile
#define CHUNKS_PAD 4160      // pad for wave0's clamped 9th DMA instr
#define TFLOAT (ROWS * NBINS)

// Async DMA one tile (66KB) global->LDS. 8 instrs/thread + 1 extra for wave0.
// LDS dest linear in lane order (wave-uniform base + lane*16) as required.
__device__ __forceinline__ void stage(const float* __restrict__ x, int tg,
                                      float* ldst, int tid, int wv, int lane) {
    const float* gsrc = x + (size_t)tg * TFLOAT;
#pragma unroll
    for (int j = 0; j < 8; ++j) {                  // chunks 0..4095
        int ci = tid + j * BLOCK;
        __builtin_amdgcn_global_load_lds(
            (const __attribute__((address_space(1))) void*)(gsrc + ci * 4),
            (__attribute__((address_space(3))) void*)(ldst + ci * 4), 16, 0, 0);
    }
    if (wv == 0) {                                 // chunks 4096..4111 (+pad)
        int ci = 4096 + lane;
        int cs = ci <= 4111 ? ci : 4111;           // clamp src; excess -> pad
        __builtin_amdgcn_global_load_lds(
            (const __attribute__((address_space(1))) void*)(gsrc + cs * 4),
            (__attribute__((address_space(3))) void*)(ldst + ci * 4), 16, 0, 0);
    }
}

// Streaming per-bin weights: bin k in segment s contributes wr[k] to filter s
// (rise) and wf[k] to filter s-1 (fall). Each wave owns filters [fa,fb) and
// sweeps segments fa..fb (1-seg overlap with neighbor, no handoff). All loop
// bounds wave-uniform (scalar control). Output staged in LDS (sout) and
// stored coalesced; counted-vmcnt keeps next-next tile's DMA in flight.
__global__ __launch_bounds__(BLOCK, 2) void filter_kernel(
        const float* __restrict__ x, const float* __restrict__ bp,
        float* __restrict__ out, int tiles) {
    __shared__ __align__(16) float sx[2][CHUNKS_PAD * 4];  // 133120 B
    __shared__ float sout[ROWS * OPAD];                    // 20736 B
    __shared__ __align__(8)  float sw[2 * NBINS];          // 2056 B
    __shared__ float sb[NPTS];
    __shared__ int   sli[NPTS];                            // floor(b[s])
    __shared__ int   sflag;
    // total ~156.9 KB -> 1 block/CU, 8 waves

    const int tid  = threadIdx.x;
    const int lane = tid & 63;
    const int wv   = __builtin_amdgcn_readfirstlane(tid >> 6);

    const int bid  = blockIdx.x;
    const int base = tiles / GRID, rem = tiles % GRID;
    const int t0   = bid * base + min(bid, rem);
    const int cnt  = base + (bid < rem ? 1 : 0);
    if (cnt <= 0) return;

    // ---- prologue: T0 DMA first, table prep under its latency ----
    stage(x, t0, &sx[0][0], tid, wv, lane);
    if (tid == 0) sflag = 0;
    if (tid < NPTS) sb[tid] = bp[tid];
    for (int i = tid; i < 2 * NBINS; i += BLOCK) sw[i] = 0.f;
    __syncthreads();
    if (tid < NPTS - 1 && sb[tid] > sb[tid + 1]) sflag = 1;
    __syncthreads();
    if (sflag) {                           // input unsorted (not expected)
        if (tid == 0) {
            for (int i = 1; i < NPTS; ++i) {
                float v = sb[i]; int j = i - 1;
                while (j >= 0 && sb[j] > v) { sb[j + 1] = sb[j]; --j; }
                sb[j + 1] = v;
            }
        }
        __syncthreads();
    }
    if (tid <= 80) sli[tid] = (int)floorf(sb[tid]);
    __syncthreads();
    if (tid < 80) {                        // thread s fills its segment's bins
        int s  = tid;
        int k0 = sli[s], k1 = sli[s + 1];
        float bs = sb[s], bs1 = sb[s + 1];
        float d = bs1 - bs, D = d * d;
        float invD = (D == 0.f) ? 1.f : 1.f / D;
        for (int k = k0; k < k1; ++k) {
            sw[2 * k]     = (s <= 78) ? ((float)k - bs) * invD : 0.f;  // rise(s)
            sw[2 * k + 1] = (s >= 1)  ? (bs1 - (float)k) * invD : 0.f; // fall(s-1)
        }
    }
    asm volatile("s_waitcnt vmcnt(0)" ::: "memory");   // T0 + bp landed
    __syncthreads();                                   // tables visible

    if (cnt > 1) stage(x, t0 + 1, &sx[1][0], tid, wv, lane);  // T1 in flight

    const float2* swp = (const float2*)sw;
    const int fa = (79 * wv) / NW;         // filter range [fa, fb)
    const int fb = (79 * (wv + 1)) / NW;

    for (int tl = 0; tl < cnt; ++tl) {
        // invariant: T_tl landed (all waves); T_{tl+1} in flight (8|9/wave)
        const float* xr = &sx[tl & 1][lane * NBINS];
        float* so = sout + lane * OPAD;

        // ---- compute: sweep segments fa..fb, emit filters to sout ----
        int k = __builtin_amdgcn_readfirstlane(sli[fa]);
        float r_prev = 0.f;
        for (int s = fa; s <= fb; ++s) {
            const int k1 = __builtin_amdgcn_readfirstlane(sli[s + 1]);
            float racc = 0.f, facc = 0.f;
            while (k < k1) {
                float  xv = xr[k];
                float2 w2 = swp[k];        // broadcast (same addr all lanes)
                racc = fmaf(xv, w2.x, racc);
                facc = fmaf(xv, w2.y, facc);
                ++k;
            }
            if (s > fa) {
                int f = s - 1;
                if (f > 0) so[f] = r_prev + facc;   // f==0 special-cased below
            }
            r_prev = racc;
        }
        if (wv == 0) {
            so[0] = xr[0];                 // filtered[:,:,0] = x[:,:,0]
            so[NFILT - 1] = 0.f;           // fbank row 79 is zeros
        }

        asm volatile("s_waitcnt lgkmcnt(0)" ::: "memory");
        __builtin_amdgcn_s_barrier();      // B1: sout complete; sx[cur] free
        __builtin_amdgcn_sched_barrier(0);

        // ---- coalesced store of the 64x80 tile (4 txns per wave-instr) ----
        float* ob = out + (size_t)(t0 + tl) * (ROWS * NFILT);
#pragma unroll
        for (int j = 0; j < (ROWS * NFILT) / BLOCK; ++j) {   // 10 per thread
            int i = tid + j * BLOCK;
            int r = i / NFILT;
            ob[i] = sout[r * OPAD + (i - r * NFILT)];
        }
        __builtin_amdgcn_sched_barrier(0); // keep stores issued BEFORE new DMA

        if (tl == cnt - 1) break;          // stores drain at kernel end

        if (tl + 2 < cnt) {
            stage(x, t0 + tl + 2, &sx[tl & 1][0], tid, wv, lane);
            __builtin_amdgcn_sched_barrier(0);
            // outstanding: T_{tl+1}(old) + stores(mid) + T_{tl+2}(new 8|9).
            // keep only the new DMA in flight:
            if (wv == 0) asm volatile("s_waitcnt vmcnt(9)" ::: "memory");
            else         asm volatile("s_waitcnt vmcnt(8)" ::: "memory");
        } else {
            asm volatile("s_waitcnt vmcnt(0)" ::: "memory");
        }
        __builtin_amdgcn_sched_barrier(0);
        asm volatile("s_waitcnt lgkmcnt(0)" ::: "memory");
        __builtin_amdgcn_s_barrier();      // B2: T_{tl+1} landed for all waves;
        __builtin_amdgcn_sched_barrier(0); //     sout reusable
    }
}

extern "C" void kernel_launch(void* const* d_in, const int* in_sizes, int n_in,
                              void* d_out, int out_size, void* d_ws, size_t ws_size,
                              hipStream_t stream) {
    const float* x  = (const float*)d_in[0];
    const float* bp = (const float*)d_in[1];
    float* out = (float*)d_out;

    const int nrows = in_sizes[0] / NBINS;   // 131072
    const int tiles = nrows / ROWS;          // 2048

    filter_kernel<<<GRID, BLOCK, 0, stream>>>(x, bp, out, tiles);
}

// Round 8
// 37.606 us; speedup vs baseline: 2.6130x; 1.3461x over previous
//
#include <hip/hip_runtime.h>

#define NFILT 80
#define NBINS 257            // 512/2+1
#define NPTS  82             // binpoints
#define ROWS  64             // rows per tile (= lanes)
#define BLOCK 512            // 8 waves
#define NW    8
#define GRID  512            // 2 blocks per CU
#define OPAD  81             // sout row stride: bank=(17*lane+f)%32, conflict-free
#define CHUNKS 4112          // 64*257/4 float4 chunks per tile
#define CHUNKS_PAD 4160      // pad for wave0's clamped extra DMA instrs
#define TFLOAT (ROWS * NBINS)
#define FPW   10             // filters per wave (wave w owns [10w, 10w+10))

// Async DMA one tile (66KB) global->LDS. 8 instrs/thread + 1 extra for wave0.
// LDS dest linear in lane order (wave-uniform base + lane*16) as required.
__device__ __forceinline__ void stage(const float* __restrict__ x, int tg,
                                      float* ldst, int tid, int wv, int lane) {
    const float* gsrc = x + (size_t)tg * TFLOAT;
#pragma unroll
    for (int j = 0; j < 8; ++j) {                  // chunks 0..4095
        int ci = tid + j * BLOCK;
        __builtin_amdgcn_global_load_lds(
            (const __attribute__((address_space(1))) void*)(gsrc + ci * 4),
            (__attribute__((address_space(3))) void*)(ldst + ci * 4), 16, 0, 0);
    }
    if (wv == 0) {                                 // chunks 4096..4111 (+pad)
        int ci = 4096 + lane;
        int cs = ci <= 4111 ? ci : 4111;           // clamp src; excess -> pad
        __builtin_amdgcn_global_load_lds(
            (const __attribute__((address_space(1))) void*)(gsrc + cs * 4),
            (__attribute__((address_space(3))) void*)(ldst + ci * 4), 16, 0, 0);
    }
}

// Streaming per-bin weights: bin k in segment s contributes wr[k] to filter s
// (rise) and wf[k] to filter s-1 (fall). Wave w sweeps segments 10w..10w+10
// (1-segment overlap with neighbor) holding 10 outputs in REGISTERS (res[],
// statically indexed via full unroll), then writes them into the head of sx
// (the x-tile is dead by then) for a coalesced store. Single-buffered;
// 2 independent blocks/CU provide the stage/compute overlap.
__global__ __launch_bounds__(BLOCK, 4) void filter_kernel(
        const float* __restrict__ x, const float* __restrict__ bp,
        float* __restrict__ out, int tiles) {
    __shared__ __align__(16) float sx[CHUNKS_PAD * 4];     // 66560 B
    __shared__ __align__(8)  float sw[2 * NBINS];          // 2056 B
    __shared__ float sb[NPTS];                             // 328 B
    __shared__ int   sli[NPTS];                            // 328 B  floor(b[s])
    __shared__ int   sflag;
    // total ~69.3 KB -> 2 blocks/CU, 16 waves/CU

    const int tid  = threadIdx.x;
    const int lane = tid & 63;
    const int wv   = __builtin_amdgcn_readfirstlane(tid >> 6);

    const int bid  = blockIdx.x;
    const int base = tiles / GRID, rem = tiles % GRID;
    const int t0   = bid * base + min(bid, rem);
    const int cnt  = base + (bid < rem ? 1 : 0);
    if (cnt <= 0) return;

    // ---- prologue: T0 DMA first, table prep under its latency ----
    stage(x, t0, sx, tid, wv, lane);
    if (tid == 0) sflag = 0;
    if (tid < NPTS) sb[tid] = bp[tid];
    for (int i = tid; i < 2 * NBINS; i += BLOCK) sw[i] = 0.f;
    __syncthreads();
    if (tid < NPTS - 1 && sb[tid] > sb[tid + 1]) sflag = 1;
    __syncthreads();
    if (sflag) {                           // input unsorted (not expected)
        if (tid == 0) {
            for (int i = 1; i < NPTS; ++i) {
                float v = sb[i]; int j = i - 1;
                while (j >= 0 && sb[j] > v) { sb[j + 1] = sb[j]; --j; }
                sb[j + 1] = v;
            }
        }
        __syncthreads();
    }
    if (tid <= 80) sli[tid] = (int)floorf(sb[tid]);
    if (tid == 81) sli[81] = (int)floorf(sb[80]);   // sentinel: empty seg 80+
    __syncthreads();
    if (tid < 80) {                        // thread s fills its segment's bins
        int s  = tid;
        int k0 = sli[s], k1 = sli[s + 1];
        float bs = sb[s], bs1 = sb[s + 1];
        float d = bs1 - bs, D = d * d;
        float invD = (D == 0.f) ? 1.f : 1.f / D;
        for (int k = k0; k < k1; ++k) {
            sw[2 * k]     = (s <= 78) ? ((float)k - bs) * invD : 0.f;  // rise(s)
            sw[2 * k + 1] = (s >= 1)  ? (bs1 - (float)k) * invD : 0.f; // fall(s-1)
        }
    }
    asm volatile("s_waitcnt vmcnt(0)" ::: "memory");   // T0 + bp landed
    __syncthreads();                                   // tables visible

    const float2* swp = (const float2*)sw;
    const int fa = FPW * wv;               // wave owns filters [fa, fa+10)

    for (int tl = 0; tl < cnt; ++tl) {
        // head invariant: sx holds tile tl, landed for all waves
        const float* xr = &sx[lane * NBINS];

        // ---- compute: sweep 11 segments, hold 10 outputs in registers ----
        float res[FPW];
        float xv0 = xr[0];                 // for wave0's filter-0 overwrite
        int k = __builtin_amdgcn_readfirstlane(sli[fa]);
        float r_prev = 0.f;
#pragma unroll
        for (int e = 0; e <= FPW; ++e) {   // full unroll -> static res indices
            const int s  = fa + e;
            const int k1 = __builtin_amdgcn_readfirstlane(sli[s + 1]);
            float racc = 0.f, facc = 0.f;
            if (k < k1) {                  // load-ahead software pipeline
                float  xv = xr[k];
                float2 w2 = swp[k];
                for (; k + 1 < k1; ++k) {
                    float  xn = xr[k + 1];          // in flight during FMAs
                    float2 wn = swp[k + 1];
                    racc = fmaf(xv, w2.x, racc);
                    facc = fmaf(xv, w2.y, facc);
                    xv = xn; w2 = wn;
                }
                racc = fmaf(xv, w2.x, racc);
                facc = fmaf(xv, w2.y, facc);
                ++k;
            }
            if (e > 0) res[e - 1] = r_prev + facc;  // filter fa+e-1
            r_prev = racc;
        }
        if (wv == 0)      res[0] = xv0;    // filtered[:,:,0] = x[:,:,0]
        if (wv == NW - 1) res[FPW - 1] = 0.f;  // fbank row 79 is zeros

        asm volatile("s_waitcnt lgkmcnt(0)" ::: "memory");
        __builtin_amdgcn_s_barrier();      // B1: all reads of sx done -> dead
        __builtin_amdgcn_sched_barrier(0);

        // ---- write results into head of sx as [ROWS][OPAD] staging ----
        float* so = sx + lane * OPAD;
#pragma unroll
        for (int e = 0; e < FPW; ++e) so[fa + e] = res[e];

        asm volatile("s_waitcnt lgkmcnt(0)" ::: "memory");
        __builtin_amdgcn_s_barrier();      // B2: sout visible to all waves
        __builtin_amdgcn_sched_barrier(0);

        // ---- coalesced store of the 64x80 tile ----
        float* ob = out + (size_t)(t0 + tl) * (ROWS * NFILT);
#pragma unroll
        for (int j = 0; j < (ROWS * NFILT) / BLOCK; ++j) {   // 10 per thread
            int i = tid + j * BLOCK;
            int r = i / NFILT;
            ob[i] = sx[r * OPAD + (i - r * NFILT)];
        }

        if (tl == cnt - 1) break;          // stores drain at kernel end

        asm volatile("s_waitcnt lgkmcnt(0)" ::: "memory");  // store ds_reads done
        __builtin_amdgcn_s_barrier();      // B3: sx fully dead for all waves
        __builtin_amdgcn_sched_barrier(0);

        stage(x, t0 + tl + 1, sx, tid, wv, lane);
        asm volatile("s_waitcnt vmcnt(0)" ::: "memory");    // T_{tl+1} landed
        __builtin_amdgcn_s_barrier();      // B4: landed for ALL waves
        __builtin_amdgcn_sched_barrier(0);
    }
}

extern "C" void kernel_launch(void* const* d_in, const int* in_sizes, int n_in,
                              void* d_out, int out_size, void* d_ws, size_t ws_size,
                              hipStream_t stream) {
    const float* x  = (const float*)d_in[0];
    const float* bp = (const float*)d_in[1];
    float* out = (float*)d_out;

    const int nrows = in_sizes[0] / NBINS;   // 131072
    const int tiles = nrows / ROWS;          // 2048

    filter_kernel<<<GRID, BLOCK, 0, stream>>>(x, bp, out, tiles);
}